// Round 8
// baseline (8033.203 us; speedup 1.0000x reference)
//
#include <hip/hip_runtime.h>
#include <hip/hip_bf16.h>

#define D 100

typedef __hip_bfloat16 bf16;

__device__ __forceinline__ float ldf(const void* p, long long i, int f32) {
    return f32 ? ((const float*)p)[i] : __bfloat162float(((const bf16*)p)[i]);
}

// ---------- input dtype detector: 0 = bf16, 1 = fp32 ----------
__global__ void detectk(const void* __restrict__ emb, int* __restrict__ flag)
{
    const unsigned short* u = (const unsigned short*)emb;
    __shared__ int cnt;
    if (threadIdx.x == 0) cnt = 0;
    __syncthreads();
    int good = 0;
    for (int i = threadIdx.x; i < 512; i += 256) {
        int e = (u[i] >> 7) & 0xFF;
        if (e >= 118 && e <= 137) good++;
    }
    atomicAdd(&cnt, good);
    __syncthreads();
    if (threadIdx.x == 0) *flag = (cnt >= 410) ? 0 : 1;
}

// ---------- input conversions ----------

__global__ void convw(const void* __restrict__ wi, const void* __restrict__ w1,
    const void* __restrict__ w2, const int* __restrict__ flag, float* __restrict__ Wf)
{
    int i = blockIdx.x * 256 + threadIdx.x;
    int f = *flag;
    if (i < 30000)      Wf[i] = ldf(wi, i, f);
    else if (i < 40000) Wf[i] = ldf(w1, i - 30000, f);
    else if (i < 50000) Wf[i] = ldf(w2, i - 40000, f);
}

// o0, o1 are FLOAT32 (output dtype follows the reference: jnp.float32).
__global__ void initk(const void* __restrict__ emb, const int* __restrict__ flag,
    bf16* __restrict__ x, float* __restrict__ o0, float* __restrict__ o1, int n)
{
    int i = blockIdx.x * 256 + threadIdx.x;
    if (i < n) {
        float v = ldf(emb, i, *flag);
        x[i] = __float2bfloat16(v);
        o0[i] = v;          // final[0] = raw embedding (scaled by 1/4 in fink)
        o1[i] = 0.0f;
    }
}

__global__ void fink(float* __restrict__ o0, float* __restrict__ o1, int nd)
{
    int i = blockIdx.x * 256 + threadIdx.x;
    if (i < nd) {
        o0[i] *= 0.25f;             // /(L+1)
        o1[i] *= (1.0f / 3.0f);     // /L
    }
}

// ---------- naive GEMM: Y[n,c] = sum_d X[n,d] * W[d,c] ----------

__global__ void mm_naive(const bf16* __restrict__ X, const float* __restrict__ W,
    bf16* __restrict__ Y, int n)
{
    long long t = (long long)blockIdx.x * 256 + threadIdx.x;
    if (t >= (long long)n * D) return;
    int nn = (int)(t / D), c = (int)(t - (long long)nn * D);
    const bf16* xr = X + (long long)nn * D;
    float acc = 0.f;
    for (int d = 0; d < D; ++d)
        acc = fmaf(__bfloat162float(xr[d]), W[d * D + c], acc);
    Y[t] = __float2bfloat16(acc);
}

// ---------- naive: Y = relu(X @ W + X) ----------

__global__ void mm_addrelu(const bf16* __restrict__ X, const float* __restrict__ W,
    bf16* __restrict__ Y, int n)
{
    long long t = (long long)blockIdx.x * 256 + threadIdx.x;
    if (t >= (long long)n * D) return;
    int nn = (int)(t / D), c = (int)(t - (long long)nn * D);
    const bf16* xr = X + (long long)nn * D;
    float acc = 0.f;
    for (int d = 0; d < D; ++d)
        acc = fmaf(__bfloat162float(xr[d]), W[d * D + c], acc);
    acc += __bfloat162float(xr[c]);
    Y[t] = __float2bfloat16(fmaxf(acc, 0.0f));
}

// ---------- COO SpMM half-pass p: S[r][dd] += v * X[c][p*50+dd] ----------

__global__ void coo_half(const int* __restrict__ rows, const int* __restrict__ cols,
    const void* __restrict__ vals, const int* __restrict__ flag,
    const bf16* __restrict__ X, float* __restrict__ S, int p, int n, int nnz)
{
    long long t = (long long)blockIdx.x * 256 + threadIdx.x;
    if (t >= (long long)nnz * 50) return;
    int e = (int)(t / 50), dd = (int)(t - (long long)e * 50);
    int r = rows[e], c = cols[e];
    if ((unsigned)r >= (unsigned)n || (unsigned)c >= (unsigned)n) return;
    float v = ldf(vals, e, *flag);
    atomicAdd(&S[(long long)r * 50 + dd],
              v * __bfloat162float(X[(long long)c * D + p * 50 + dd]));
}

__global__ void cvt_half(const float* __restrict__ S, bf16* __restrict__ X2, int p, int n)
{
    long long t = (long long)blockIdx.x * 256 + threadIdx.x;
    if (t >= (long long)n * 50) return;
    int nn = (int)(t / 50), dd = (int)(t - (long long)nn * 50);
    X2[(long long)nn * D + p * 50 + dd] = __float2bfloat16(S[t]);
}

// ---------- in-place row softmax on bf16 [n, D] ----------

__global__ void softmax_rows(bf16* __restrict__ L, int n)
{
    __shared__ float red[128];
    __shared__ float m_s, s_s;
    int r = blockIdx.x;
    if (r >= n) return;
    int d = threadIdx.x;
    float x = (d < D) ? __bfloat162float(L[(long long)r * D + d]) : -3.0e38f;
    red[d] = x; __syncthreads();
    for (int off = 64; off; off >>= 1) {
        if (d < off) red[d] = fmaxf(red[d], red[d + off]);
        __syncthreads();
    }
    if (d == 0) m_s = red[0];
    __syncthreads();
    float e = (d < D) ? __expf(x - m_s) : 0.0f;
    red[d] = e; __syncthreads();
    for (int off = 64; off; off >>= 1) {
        if (d < off) red[d] += red[d + off];
        __syncthreads();
    }
    if (d == 0) s_s = red[0];
    __syncthreads();
    if (d < D) L[(long long)r * D + d] = __float2bfloat16(e / s_s);
}

// ---------- hsm[k,d] = sum_n H1[n,k] * X2[n,d]  (block per (k,chunk)) ----------

__global__ void hsm_k(const bf16* __restrict__ H1, const bf16* __restrict__ X2,
    float* __restrict__ hsm, int n)
{
    int k = blockIdx.x;
    int chunk = blockIdx.y;
    int d = threadIdx.x;
    if (d >= D) return;
    int per = (n + 31) / 32;
    int s = chunk * per, e = s + per;
    if (e > n) e = n;
    float acc = 0.f;
    for (int nn = s; nn < e; ++nn)
        acc = fmaf(__bfloat162float(H1[(long long)nn * D + k]),
                   __bfloat162float(X2[(long long)nn * D + d]), acc);
    atomicAdd(&hsm[k * D + d], acc);
}

// ---- finrow: x_new = hN + x2 (into X); o0 += l2n(x_new); o1 += l2n(hN) (fp32) ----

__global__ void finrow(const bf16* __restrict__ Hn, bf16* __restrict__ X,
    float* __restrict__ o0, float* __restrict__ o1, int n)
{
    __shared__ float red[128];
    __shared__ float ia_s, ib_s;
    int r = blockIdx.x;
    if (r >= n) return;
    int d = threadIdx.x;
    long long b = (long long)r * D;
    float hn = (d < D) ? __bfloat162float(Hn[b + d]) : 0.f;
    float x2 = (d < D) ? __bfloat162float(X[b + d]) : 0.f;
    float xn = hn + x2;
    red[d] = xn * xn; __syncthreads();
    for (int off = 64; off; off >>= 1) {
        if (d < off) red[d] += red[d + off];
        __syncthreads();
    }
    if (d == 0) ia_s = 1.0f / fmaxf(sqrtf(red[0]), 1e-12f);
    __syncthreads();
    red[d] = hn * hn; __syncthreads();
    for (int off = 64; off; off >>= 1) {
        if (d < off) red[d] += red[d + off];
        __syncthreads();
    }
    if (d == 0) ib_s = 1.0f / fmaxf(sqrtf(red[0]), 1e-12f);
    __syncthreads();
    if (d < D) {
        X[b + d] = __float2bfloat16(xn);
        o0[b + d] += xn * ia_s;
        o1[b + d] += hn * ib_s;
    }
}

// ---------- host ----------

extern "C" void kernel_launch(void* const* d_in, const int* in_sizes, int n_in,
                              void* d_out, int out_size, void* d_ws, size_t ws_size,
                              hipStream_t stream)
{
    const void* emb   = d_in[0];
    // d_in[1] = adj: cancels exactly in column-normalization (softmax rows sum to 1)
    const void* evals = d_in[2];
    const void* Wit   = d_in[3];
    const void* Wi1   = d_in[4];
    const void* Wi2   = d_in[5];
    const int* erows  = (const int*)d_in[6];
    const int* ecols  = (const int*)d_in[7];
    const int N   = in_sizes[0] / D;
    const int NNZ = in_sizes[2];
    const long long ND = (long long)N * D;

    float* o0 = (float*)d_out;      // item_embeddings accumulator (fp32 output!)
    float* o1 = o0 + ND;            // hs accumulator

    char* base = (char*)d_ws;
    size_t off = 0;
    auto alloc = [&](size_t bytes) -> void* {
        void* r = base + off;
        off += (bytes + 255) & ~(size_t)255;
        return r;
    };
    int*   flag = (int*)  alloc(256);
    float* hsm  = (float*)alloc(D * D * 4);
    float* Wf   = (float*)alloc(5 * D * D * 4);
    bf16*  B1   = (bf16*) alloc(ND * 2);
    bf16*  B2   = (bf16*) alloc(ND * 2);
    float* S20  = (float*)alloc((size_t)N * 50 * 4);
    bf16*  H1   = (bf16*)S20;   // alias: spmm scratch reused as H1 after cvt

    const int gND = (int)((ND + 255) / 256);
    const int gE  = (int)(((long long)NNZ * 50 + 255) / 256);
    const int gH  = (int)(((long long)N * 50 + 255) / 256);

    detectk<<<1, 256, 0, stream>>>(emb, flag);
    convw<<<(50000 + 255) / 256, 256, 0, stream>>>(Wit, Wi1, Wi2, flag, Wf);
    initk<<<gND, 256, 0, stream>>>(emb, flag, B1, o0, o1, (int)ND);

    for (int l = 0; l < 3; ++l) {
        mm_naive<<<gND, 256, 0, stream>>>(B1, Wf + l * 10000, B2, N);   // B2 = x@W
        for (int p = 0; p < 2; ++p) {                                   // B1 = A@B2
            hipMemsetAsync(S20, 0, (size_t)N * 50 * 4, stream);
            coo_half<<<gE, 256, 0, stream>>>(erows, ecols, evals, flag, B2, S20, p, N, NNZ);
            cvt_half<<<gH, 256, 0, stream>>>(S20, B1, p, N);
        }
        mm_addrelu<<<gND, 256, 0, stream>>>(B1, Wf + 30000, B2, N);     // B2 = relu(x2@W1+x2)
        mm_naive<<<gND, 256, 0, stream>>>(B2, Wf + 40000, H1, N);       // H1 = logits
        softmax_rows<<<N, 128, 0, stream>>>(H1, N);                     // H1 = softmax
        hipMemsetAsync(hsm, 0, D * D * 4, stream);
        hsm_k<<<dim3(D, 32), 128, 0, stream>>>(H1, B1, hsm, N);         // hsm = H1^T@x2
        mm_naive<<<gND, 256, 0, stream>>>(H1, hsm, B2, N);              // B2 = hN
        finrow<<<N, 128, 0, stream>>>(B2, B1, o0, o1, N);               // B1 = x_new; accum
    }
    fink<<<gND, 256, 0, stream>>>(o0, o1, (int)ND);
}